// Round 1
// baseline (743.057 us; speedup 1.0000x reference)
//
#include <hip/hip_runtime.h>
#include <hip/hip_bf16.h>
#include <math.h>

typedef __bf16 bf16_t;
typedef __bf16 bf16x8 __attribute__((ext_vector_type(8)));
typedef float  f32x4  __attribute__((ext_vector_type(4)));

#define DEV __device__ __forceinline__

#define BSZ    4
#define SEQ    2048
#define DMODEL 1024
#define NHEADS 16
#define HDIM   64
#define MROWS  (BSZ*SEQ)      /* 8192 */
#define KDIM   1024           /* K for both GEMMs */
#define NQKV   (3*DMODEL)     /* 3072 */

// async global->LDS, 16B per lane; LDS dest must be wave-uniform base + lane*16
#define GLOAD_LDS16(src, dst)                                                  \
  __builtin_amdgcn_global_load_lds(                                            \
      (__attribute__((address_space(1))) void*)(void*)(src),                   \
      (__attribute__((address_space(3))) void*)(dst), 16, 0, 0)

// ---------------------------------------------------------------- cast kernel
__global__ void cast_f32_to_bf16(const float* __restrict__ in,
                                 bf16_t* __restrict__ out, int n4) {
  union U { bf16_t b[4]; uint2 u; };
  for (int i = blockIdx.x * blockDim.x + threadIdx.x; i < n4;
       i += gridDim.x * blockDim.x) {
    float4 v = reinterpret_cast<const float4*>(in)[i];
    U r;
    r.b[0] = (bf16_t)v.x; r.b[1] = (bf16_t)v.y;
    r.b[2] = (bf16_t)v.z; r.b[3] = (bf16_t)v.w;
    reinterpret_cast<uint2*>(out)[i] = r.u;
  }
}

// ---------------------------------------------------------------- GEMM core
// C_tile[128x128] = A[row0:+128, 0:1024] * Bt[col0:+128, 0:1024]^T
// A, Bt row-major bf16 with K contiguous. LDS tiles are [128 rows][128 bytes]
// with byte ^= ((row&7)<<4) XOR swizzle; staging pre-swizzles the GLOBAL source
// so the linear global_load_lds dest stays correct (guide §5 / m173 pattern).
DEV void gemm_tile(const bf16_t* __restrict__ A, const bf16_t* __restrict__ Bt,
                   int row0, int col0, char* smem, f32x4 acc[4][4]) {
  const int t    = threadIdx.x;
  const int lane = t & 63;
  const int wid  = t >> 6;
  const int wm   = (wid >> 1) * 64;
  const int wn   = (wid & 1) * 64;
  const int l15  = lane & 15;
  const int lhi  = lane >> 4;

  char* As = smem;
  char* Bs = smem + 16384;

  const f32x4 fzero = {0.f, 0.f, 0.f, 0.f};
#pragma unroll
  for (int mi = 0; mi < 4; mi++)
#pragma unroll
    for (int ni = 0; ni < 4; ni++) acc[mi][ni] = fzero;

  const char* Abase = (const char*)A;
  const char* Bbase = (const char*)Bt;

  for (int k0 = 0; k0 < KDIM; k0 += 64) {
    __syncthreads();  // previous iter's LDS reads complete
#pragma unroll
    for (int i = 0; i < 4; i++) {
      int o   = (t + i * 256) * 16;                 // 0..16K-16
      int row = o >> 7;
      int cbs = (o & 127) ^ ((row & 7) << 4);       // pre-swizzled source col
      GLOAD_LDS16(Abase + ((size_t)(row0 + row) * KDIM + k0) * 2 + cbs, As + o);
      GLOAD_LDS16(Bbase + ((size_t)(col0 + row) * KDIM + k0) * 2 + cbs, Bs + o);
    }
    __syncthreads();  // drains vmcnt: tiles ready

#pragma unroll
    for (int ks = 0; ks < 2; ks++) {
      bf16x8 a[4], b[4];
      int byt = ks * 64 + lhi * 16;
#pragma unroll
      for (int mi = 0; mi < 4; mi++) {
        int r = wm + mi * 16 + l15;
        a[mi] = *(const bf16x8*)(As + r * 128 + (byt ^ ((r & 7) << 4)));
      }
#pragma unroll
      for (int ni = 0; ni < 4; ni++) {
        int r = wn + ni * 16 + l15;
        b[ni] = *(const bf16x8*)(Bs + r * 128 + (byt ^ ((r & 7) << 4)));
      }
#pragma unroll
      for (int mi = 0; mi < 4; mi++)
#pragma unroll
        for (int ni = 0; ni < 4; ni++)
          acc[mi][ni] = __builtin_amdgcn_mfma_f32_16x16x32_bf16(
              a[mi], b[ni], acc[mi][ni], 0, 0, 0);
    }
  }
}

// ------------------------------------------------- QKV projection + scatter
// qkv[m, n] = x[m,:] . W[n,:] + bias[n];  n<1024 -> Q, <2048 -> K, else -> V
// Q,K stored [b*16+h][s][64]; V stored TRANSPOSED [b*16+h][d][2048].
__global__ void gemm_qkv_kernel(const bf16_t* __restrict__ xb,
                                const bf16_t* __restrict__ wqkv,
                                const float* __restrict__ bias,
                                bf16_t* __restrict__ Qg, bf16_t* __restrict__ Kg,
                                bf16_t* __restrict__ Vt) {
  __shared__ char smem[32768];
  f32x4 acc[4][4];
  const int bx = blockIdx.x;
  const int mt = bx / 24, nt = bx % 24;
  const int row0 = mt * 128, col0 = nt * 128;
  gemm_tile(xb, wqkv, row0, col0, smem, acc);

  const int t = threadIdx.x, lane = t & 63, wid = t >> 6;
  const int wm = (wid >> 1) * 64, wn = (wid & 1) * 64;
  const int l15 = lane & 15, lhi = lane >> 4;
#pragma unroll
  for (int mi = 0; mi < 4; mi++)
#pragma unroll
    for (int ni = 0; ni < 4; ni++)
#pragma unroll
      for (int j = 0; j < 4; j++) {
        int m = row0 + wm + mi * 16 + lhi * 4 + j;
        int n = col0 + wn + ni * 16 + l15;
        float v = acc[mi][ni][j] + bias[n];
        bf16_t bv = (bf16_t)v;
        int b = m >> 11, s = m & 2047;
        int which = n >> 10, rem = n & 1023;
        int h = rem >> 6, d = rem & 63;
        size_t bh = (size_t)(b * NHEADS + h);
        if (which == 0)      Qg[(bh * SEQ + s) * HDIM + d] = bv;
        else if (which == 1) Kg[(bh * SEQ + s) * HDIM + d] = bv;
        else                 Vt[(bh * HDIM + d) * SEQ + s] = bv;
      }
}

// ------------------------------------------------------------ out projection
__global__ void gemm_out_kernel(const bf16_t* __restrict__ Og,
                                const bf16_t* __restrict__ wo,
                                const float* __restrict__ bias,
                                float* __restrict__ out) {
  __shared__ char smem[32768];
  f32x4 acc[4][4];
  const int bx = blockIdx.x;
  const int mt = bx >> 3, nt = bx & 7;
  const int row0 = mt * 128, col0 = nt * 128;
  gemm_tile(Og, wo, row0, col0, smem, acc);

  const int t = threadIdx.x, lane = t & 63, wid = t >> 6;
  const int wm = (wid >> 1) * 64, wn = (wid & 1) * 64;
  const int l15 = lane & 15, lhi = lane >> 4;
#pragma unroll
  for (int mi = 0; mi < 4; mi++)
#pragma unroll
    for (int ni = 0; ni < 4; ni++)
#pragma unroll
      for (int j = 0; j < 4; j++) {
        int m = row0 + wm + mi * 16 + lhi * 4 + j;
        int n = col0 + wn + ni * 16 + l15;
        out[(size_t)m * DMODEL + n] = acc[mi][ni][j] + bias[n];
      }
}

// ------------------------------------------------------------ flash attention
// grid = 64 (b*h) * 16 (q-tiles of 128). 4 waves, each owns 32 q-rows.
// K tile [64 keys][64 d], V^T tile [64 d][64 s], both LDS-swizzled.
// Online softmax wave-parallel via 16-lane shfl_xor groups.
__global__ void attn_kernel(const bf16_t* __restrict__ Qg,
                            const bf16_t* __restrict__ Kg,
                            const bf16_t* __restrict__ Vt,
                            bf16_t* __restrict__ Og) {
  __shared__ char smem[49152];
  char* Qs = smem;            // 16KB [128][128B]
  char* Ks = smem + 16384;    //  8KB [64][128B]
  char* Vs = smem + 24576;    //  8KB [64][128B]  (rows = d, cols = s)
  char* Ps = smem + 32768;    // 16KB [128][128B] (P, per-wave private rows)

  const int t = threadIdx.x, lane = t & 63, w = t >> 6;
  const int l15 = lane & 15, lhi = lane >> 4;
  const int bh = blockIdx.x >> 4, qt = blockIdx.x & 15;

  const char* Qb = (const char*)Qg + ((size_t)bh * SEQ + qt * 128) * HDIM * 2;
  const char* Kb = (const char*)Kg + (size_t)bh * SEQ * HDIM * 2;
  const char* Vb = (const char*)Vt + (size_t)bh * HDIM * SEQ * 2;

  // stage Q tile (once)
#pragma unroll
  for (int i = 0; i < 4; i++) {
    int o = (t + i * 256) * 16;
    int row = o >> 7;
    int cbs = (o & 127) ^ ((row & 7) << 4);
    GLOAD_LDS16(Qb + (size_t)row * 128 + cbs, Qs + o);
  }

  const f32x4 fzero = {0.f, 0.f, 0.f, 0.f};
  float mrun[2][4], lrun[2][4];
  f32x4 oacc[2][4];
#pragma unroll
  for (int mi = 0; mi < 2; mi++) {
#pragma unroll
    for (int j = 0; j < 4; j++) { mrun[mi][j] = -INFINITY; lrun[mi][j] = 0.f; }
#pragma unroll
    for (int db = 0; db < 4; db++) oacc[mi][db] = fzero;
  }

  __syncthreads();
  // Q fragments live in registers for the whole kernel
  bf16x8 qf[2][2];
#pragma unroll
  for (int mi = 0; mi < 2; mi++)
#pragma unroll
    for (int ks = 0; ks < 2; ks++) {
      int r = w * 32 + mi * 16 + l15;
      int byt = ks * 64 + lhi * 16;
      qf[mi][ks] = *(const bf16x8*)(Qs + r * 128 + (byt ^ ((r & 7) << 4)));
    }

  const float scale = 0.125f;  // 64^-0.5

  for (int kt = 0; kt < SEQ / 64; kt++) {
    __syncthreads();  // all waves done reading previous K/V tiles
#pragma unroll
    for (int i = 0; i < 2; i++) {
      int o = (t + i * 256) * 16;
      int row = o >> 7;
      int cbs = (o & 127) ^ ((row & 7) << 4);
      GLOAD_LDS16(Kb + (size_t)(kt * 64 + row) * 128 + cbs, Ks + o);
      GLOAD_LDS16(Vb + (size_t)row * 4096 + kt * 128 + cbs, Vs + o);
    }
    __syncthreads();

    // S = Q K^T (raw, scale folded into softmax)
    f32x4 sacc[2][4];
#pragma unroll
    for (int mi = 0; mi < 2; mi++)
#pragma unroll
      for (int ni = 0; ni < 4; ni++) sacc[mi][ni] = fzero;
#pragma unroll
    for (int ks = 0; ks < 2; ks++) {
      bf16x8 kf[4];
      int byt = ks * 64 + lhi * 16;
#pragma unroll
      for (int ni = 0; ni < 4; ni++) {
        int r = ni * 16 + l15;
        kf[ni] = *(const bf16x8*)(Ks + r * 128 + (byt ^ ((r & 7) << 4)));
      }
#pragma unroll
      for (int mi = 0; mi < 2; mi++)
#pragma unroll
        for (int ni = 0; ni < 4; ni++)
          sacc[mi][ni] = __builtin_amdgcn_mfma_f32_16x16x32_bf16(
              qf[mi][ks], kf[ni], sacc[mi][ni], 0, 0, 0);
    }

    // online softmax: row = w*32 + mi*16 + lhi*4 + j, cols = ni*16 + l15
#pragma unroll
    for (int mi = 0; mi < 2; mi++)
#pragma unroll
      for (int j = 0; j < 4; j++) {
        float mx = fmaxf(fmaxf(sacc[mi][0][j], sacc[mi][1][j]),
                         fmaxf(sacc[mi][2][j], sacc[mi][3][j]));
        mx = fmaxf(mx, __shfl_xor(mx, 1, 64));
        mx = fmaxf(mx, __shfl_xor(mx, 2, 64));
        mx = fmaxf(mx, __shfl_xor(mx, 4, 64));
        mx = fmaxf(mx, __shfl_xor(mx, 8, 64));
        mx *= scale;
        float mnew = fmaxf(mrun[mi][j], mx);
        float corr = __expf(mrun[mi][j] - mnew);  // first iter: exp(-inf)=0
        mrun[mi][j] = mnew;
        float p[4], ps = 0.f;
#pragma unroll
        for (int ni = 0; ni < 4; ni++) {
          p[ni] = __expf(sacc[mi][ni][j] * scale - mnew);
          ps += p[ni];
        }
        ps += __shfl_xor(ps, 1, 64);
        ps += __shfl_xor(ps, 2, 64);
        ps += __shfl_xor(ps, 4, 64);
        ps += __shfl_xor(ps, 8, 64);
        lrun[mi][j] = lrun[mi][j] * corr + ps;
#pragma unroll
        for (int db = 0; db < 4; db++) oacc[mi][db][j] *= corr;
        // write P (bf16) into swizzled LDS for the PV A-operand
        int r = w * 32 + mi * 16 + lhi * 4 + j;
        int sw = (r & 7) << 4;
#pragma unroll
        for (int ni = 0; ni < 4; ni++) {
          int cb = (ni * 16 + l15) * 2;
          *(bf16_t*)(Ps + r * 128 + (cb ^ sw)) = (bf16_t)p[ni];
        }
      }

    // O += P V   (P rows are per-wave private: no barrier needed)
#pragma unroll
    for (int ks = 0; ks < 2; ks++) {
      bf16x8 pf[2], vf[4];
      int byt = ks * 64 + lhi * 16;
#pragma unroll
      for (int mi = 0; mi < 2; mi++) {
        int r = w * 32 + mi * 16 + l15;
        pf[mi] = *(const bf16x8*)(Ps + r * 128 + (byt ^ ((r & 7) << 4)));
      }
#pragma unroll
      for (int db = 0; db < 4; db++) {
        int r = db * 16 + l15;
        vf[db] = *(const bf16x8*)(Vs + r * 128 + (byt ^ ((r & 7) << 4)));
      }
#pragma unroll
      for (int mi = 0; mi < 2; mi++)
#pragma unroll
        for (int db = 0; db < 4; db++)
          oacc[mi][db] = __builtin_amdgcn_mfma_f32_16x16x32_bf16(
              pf[mi], vf[db], oacc[mi][db], 0, 0, 0);
    }
  }

  // epilogue: O[b, s, h*64+d] bf16
  const int b = bh >> 4, h = bh & 15;
#pragma unroll
  for (int mi = 0; mi < 2; mi++)
#pragma unroll
    for (int db = 0; db < 4; db++)
#pragma unroll
      for (int j = 0; j < 4; j++) {
        int srow = qt * 128 + w * 32 + mi * 16 + lhi * 4 + j;
        int d = db * 16 + l15;
        float v = oacc[mi][db][j] / lrun[mi][j];
        Og[((size_t)b * SEQ + srow) * DMODEL + h * HDIM + d] = (bf16_t)v;
      }
}

// ------------------------------------------------------------------- launch
extern "C" void kernel_launch(void* const* d_in, const int* in_sizes, int n_in,
                              void* d_out, int out_size, void* d_ws,
                              size_t ws_size, hipStream_t stream) {
  (void)in_sizes; (void)n_in; (void)out_size; (void)ws_size;
  const float* x     = (const float*)d_in[0];
  const float* w_in  = (const float*)d_in[1];
  const float* b_in  = (const float*)d_in[2];
  const float* w_out = (const float*)d_in[3];
  const float* b_out = (const float*)d_in[4];
  float* out = (float*)d_out;

  char* ws = (char*)d_ws;
  bf16_t* xb  = (bf16_t*)ws; ws += (size_t)MROWS * KDIM * 2;    // 16 MB
  bf16_t* wqb = (bf16_t*)ws; ws += (size_t)NQKV * KDIM * 2;     //  6 MB
  bf16_t* wob = (bf16_t*)ws; ws += (size_t)DMODEL * KDIM * 2;   //  2 MB
  bf16_t* Qg  = (bf16_t*)ws; ws += (size_t)MROWS * DMODEL * 2;  // 16 MB
  bf16_t* Kg  = (bf16_t*)ws; ws += (size_t)MROWS * DMODEL * 2;  // 16 MB
  bf16_t* Vt  = (bf16_t*)ws; ws += (size_t)MROWS * DMODEL * 2;  // 16 MB
  bf16_t* Og  = (bf16_t*)ws; ws += (size_t)MROWS * DMODEL * 2;  // 16 MB

  cast_f32_to_bf16<<<2048, 256, 0, stream>>>(x, xb, MROWS * KDIM / 4);
  cast_f32_to_bf16<<<1024, 256, 0, stream>>>(w_in, wqb, NQKV * KDIM / 4);
  cast_f32_to_bf16<<<512, 256, 0, stream>>>(w_out, wob, DMODEL * KDIM / 4);

  gemm_qkv_kernel<<<64 * 24, 256, 0, stream>>>(xb, wqb, b_in, Qg, Kg, Vt);
  attn_kernel<<<64 * 16, 256, 0, stream>>>(Qg, Kg, Vt, Og);
  gemm_out_kernel<<<64 * 8, 256, 0, stream>>>(Og, wob, b_out, out);
}

// Round 2
// 657.304 us; speedup vs baseline: 1.1305x; 1.1305x over previous
//
#include <hip/hip_runtime.h>
#include <hip/hip_bf16.h>
#include <math.h>

typedef __bf16 bf16_t;
typedef __bf16 bf16x8 __attribute__((ext_vector_type(8)));
typedef float  f32x4  __attribute__((ext_vector_type(4)));

#define DEV __device__ __forceinline__

#define BSZ    4
#define SEQ    2048
#define DMODEL 1024
#define NHEADS 16
#define HDIM   64
#define MROWS  (BSZ*SEQ)      /* 8192 */
#define KDIM   1024           /* K for both GEMMs */
#define NQKV   (3*DMODEL)     /* 3072 */

// async global->LDS, 16B per lane; LDS dest must be wave-uniform base + lane*16
#define GLOAD_LDS16(src, dst)                                                  \
  __builtin_amdgcn_global_load_lds(                                            \
      (__attribute__((address_space(1))) void*)(void*)(src),                   \
      (__attribute__((address_space(3))) void*)(dst), 16, 0, 0)

// ---------------------------------------------------------------- cast kernel
__global__ void cast_f32_to_bf16(const float* __restrict__ in,
                                 bf16_t* __restrict__ out, int n4) {
  union U { bf16_t b[4]; uint2 u; };
  for (int i = blockIdx.x * blockDim.x + threadIdx.x; i < n4;
       i += gridDim.x * blockDim.x) {
    float4 v = reinterpret_cast<const float4*>(in)[i];
    U r;
    r.b[0] = (bf16_t)v.x; r.b[1] = (bf16_t)v.y;
    r.b[2] = (bf16_t)v.z; r.b[3] = (bf16_t)v.w;
    reinterpret_cast<uint2*>(out)[i] = r.u;
  }
}

// ---------------------------------------------------------------- GEMM core
// C_tile[128x128] = A[row0:+128, 0:1024] * Bt[col0:+128, 0:1024]^T
// A, Bt row-major bf16 with K contiguous. LDS tiles are [128 rows][128 bytes]
// with byte ^= ((row&7)<<4) XOR swizzle; staging pre-swizzles the GLOBAL source
// so the linear global_load_lds dest stays correct (guide §5 / m173 pattern).
DEV void gemm_tile(const bf16_t* __restrict__ A, const bf16_t* __restrict__ Bt,
                   int row0, int col0, char* smem, f32x4 acc[4][4]) {
  const int t    = threadIdx.x;
  const int lane = t & 63;
  const int wid  = t >> 6;
  const int wm   = (wid >> 1) * 64;
  const int wn   = (wid & 1) * 64;
  const int l15  = lane & 15;
  const int lhi  = lane >> 4;

  char* As = smem;
  char* Bs = smem + 16384;

  const f32x4 fzero = {0.f, 0.f, 0.f, 0.f};
#pragma unroll
  for (int mi = 0; mi < 4; mi++)
#pragma unroll
    for (int ni = 0; ni < 4; ni++) acc[mi][ni] = fzero;

  const char* Abase = (const char*)A;
  const char* Bbase = (const char*)Bt;

  for (int k0 = 0; k0 < KDIM; k0 += 64) {
    __syncthreads();  // previous iter's LDS reads complete
#pragma unroll
    for (int i = 0; i < 4; i++) {
      int o   = (t + i * 256) * 16;                 // 0..16K-16
      int row = o >> 7;
      int cbs = (o & 127) ^ ((row & 7) << 4);       // pre-swizzled source col
      GLOAD_LDS16(Abase + ((size_t)(row0 + row) * KDIM + k0) * 2 + cbs, As + o);
      GLOAD_LDS16(Bbase + ((size_t)(col0 + row) * KDIM + k0) * 2 + cbs, Bs + o);
    }
    __syncthreads();  // drains vmcnt: tiles ready

#pragma unroll
    for (int ks = 0; ks < 2; ks++) {
      bf16x8 a[4], b[4];
      int byt = ks * 64 + lhi * 16;
#pragma unroll
      for (int mi = 0; mi < 4; mi++) {
        int r = wm + mi * 16 + l15;
        a[mi] = *(const bf16x8*)(As + r * 128 + (byt ^ ((r & 7) << 4)));
      }
#pragma unroll
      for (int ni = 0; ni < 4; ni++) {
        int r = wn + ni * 16 + l15;
        b[ni] = *(const bf16x8*)(Bs + r * 128 + (byt ^ ((r & 7) << 4)));
      }
#pragma unroll
      for (int mi = 0; mi < 4; mi++)
#pragma unroll
        for (int ni = 0; ni < 4; ni++)
          acc[mi][ni] = __builtin_amdgcn_mfma_f32_16x16x32_bf16(
              a[mi], b[ni], acc[mi][ni], 0, 0, 0);
    }
  }
}

// ------------------------------------------------- QKV projection + scatter
// qkv[m, n] = x[m,:] . W[n,:] + bias[n];  n<1024 -> Q, <2048 -> K, else -> V
// Q,K stored [b*16+h][s][64]; V stored TRANSPOSED [b*16+h][d][2048].
// Q is pre-scaled by hd^-0.5 so attention softmax works on raw QK^T.
__global__ void gemm_qkv_kernel(const bf16_t* __restrict__ xb,
                                const bf16_t* __restrict__ wqkv,
                                const float* __restrict__ bias,
                                bf16_t* __restrict__ Qg, bf16_t* __restrict__ Kg,
                                bf16_t* __restrict__ Vt) {
  __shared__ char smem[32768];
  f32x4 acc[4][4];
  const int bx = blockIdx.x;
  const int mt = bx / 24, nt = bx % 24;
  const int row0 = mt * 128, col0 = nt * 128;
  gemm_tile(xb, wqkv, row0, col0, smem, acc);

  const int t = threadIdx.x, lane = t & 63, wid = t >> 6;
  const int wm = (wid >> 1) * 64, wn = (wid & 1) * 64;
  const int l15 = lane & 15, lhi = lane >> 4;
#pragma unroll
  for (int mi = 0; mi < 4; mi++)
#pragma unroll
    for (int ni = 0; ni < 4; ni++)
#pragma unroll
      for (int j = 0; j < 4; j++) {
        int m = row0 + wm + mi * 16 + lhi * 4 + j;
        int n = col0 + wn + ni * 16 + l15;
        float v = acc[mi][ni][j] + bias[n];
        int b = m >> 11, s = m & 2047;
        int which = n >> 10, rem = n & 1023;
        int h = rem >> 6, d = rem & 63;
        size_t bh = (size_t)(b * NHEADS + h);
        if (which == 0) {
          Qg[(bh * SEQ + s) * HDIM + d] = (bf16_t)(v * 0.125f);
        } else if (which == 1) {
          Kg[(bh * SEQ + s) * HDIM + d] = (bf16_t)v;
        } else {
          Vt[(bh * HDIM + d) * SEQ + s] = (bf16_t)v;
        }
      }
}

// ------------------------------------------------------------ out projection
__global__ void gemm_out_kernel(const bf16_t* __restrict__ Og,
                                const bf16_t* __restrict__ wo,
                                const float* __restrict__ bias,
                                float* __restrict__ out) {
  __shared__ char smem[32768];
  f32x4 acc[4][4];
  const int bx = blockIdx.x;
  const int mt = bx >> 3, nt = bx & 7;
  const int row0 = mt * 128, col0 = nt * 128;
  gemm_tile(Og, wo, row0, col0, smem, acc);

  const int t = threadIdx.x, lane = t & 63, wid = t >> 6;
  const int wm = (wid >> 1) * 64, wn = (wid & 1) * 64;
  const int l15 = lane & 15, lhi = lane >> 4;
#pragma unroll
  for (int mi = 0; mi < 4; mi++)
#pragma unroll
    for (int ni = 0; ni < 4; ni++)
#pragma unroll
      for (int j = 0; j < 4; j++) {
        int m = row0 + wm + mi * 16 + lhi * 4 + j;
        int n = col0 + wn + ni * 16 + l15;
        out[(size_t)m * DMODEL + n] = acc[mi][ni][j] + bias[n];
      }
}

// ------------------------------------------------------------ flash attention
// grid = 1024. XCD-aware remap: blockIdx i -> xcd = i&7 (round-robin dispatch),
// each XCD owns a contiguous slab of 8 bh; all 16 q-tiles of a bh share that
// XCD's L2 (512 KB K/V per bh, ~6 resident bh * 512 KB = 3 MB < 4 MB L2).
// 4 waves, each owns 32 q-rows. KVBLK=64. K/V double-buffered (2-phase
// pipeline, one barrier per kv-iter); Q staged once then its LDS region is
// recycled as buffer 0.
__global__ void attn_kernel(const bf16_t* __restrict__ Qg,
                            const bf16_t* __restrict__ Kg,
                            const bf16_t* __restrict__ Vt,
                            bf16_t* __restrict__ Og) {
  __shared__ char smem[49152];
  // buf0: [0,16384)  = K(8KB)+V(8KB)   (also initial Q staging area)
  // buf1: [16384,32768) = K+V
  // Ps:   [32768,49152)
  char* Ps = smem + 32768;

  const int t = threadIdx.x, lane = t & 63, w = t >> 6;
  const int l15 = lane & 15, lhi = lane >> 4;

  const int xcd = blockIdx.x & 7, slot = blockIdx.x >> 3;
  const int bh = xcd * 8 + (slot >> 4), qt = slot & 15;

  const char* Qb = (const char*)Qg + ((size_t)bh * SEQ + qt * 128) * HDIM * 2;
  const char* Kb = (const char*)Kg + (size_t)bh * SEQ * HDIM * 2;
  const char* Vb = (const char*)Vt + (size_t)bh * HDIM * SEQ * 2;

  // stage K/V tile for a kv-step into buffer `buf`
  auto STAGE = [&](int buf, int kt) {
    char* Kd = smem + buf * 16384;
    char* Vd = Kd + 8192;
#pragma unroll
    for (int i = 0; i < 2; i++) {
      int o   = (t + i * 256) * 16;            // 0..8176
      int row = o >> 7;                        // 0..63
      int cbs = (o & 127) ^ ((row & 7) << 4);  // pre-swizzled source col
      GLOAD_LDS16(Kb + (size_t)(kt * 64 + row) * 128 + cbs, Kd + o);
      GLOAD_LDS16(Vb + (size_t)row * 4096 + kt * 128 + cbs, Vd + o);
    }
  };

  // prologue: Q tile -> buf0 region, K/V tile 0 -> buf1, concurrently
#pragma unroll
  for (int i = 0; i < 4; i++) {
    int o = (t + i * 256) * 16;
    int row = o >> 7;
    int cbs = (o & 127) ^ ((row & 7) << 4);
    GLOAD_LDS16(Qb + (size_t)row * 128 + cbs, smem + o);
  }
  STAGE(1, 0);
  __syncthreads();  // Q + tile0 staged (vmcnt drained)

  // Q fragments -> registers for the whole kernel (Q already scaled by 1/8)
  bf16x8 qf[2][2];
#pragma unroll
  for (int mi = 0; mi < 2; mi++)
#pragma unroll
    for (int ks = 0; ks < 2; ks++) {
      int r = w * 32 + mi * 16 + l15;
      int byt = ks * 64 + lhi * 16;
      qf[mi][ks] = *(const bf16x8*)(smem + r * 128 + (byt ^ ((r & 7) << 4)));
    }

  const f32x4 fzero = {0.f, 0.f, 0.f, 0.f};
  float mrun[2][4], lrun[2][4];
  f32x4 oacc[2][4];
#pragma unroll
  for (int mi = 0; mi < 2; mi++) {
#pragma unroll
    for (int j = 0; j < 4; j++) { mrun[mi][j] = -INFINITY; lrun[mi][j] = 0.f; }
#pragma unroll
    for (int db = 0; db < 4; db++) oacc[mi][db] = fzero;
  }

  int cur = 1;
  for (int kt = 0; kt < SEQ / 64; kt++) {
    // single barrier per iter: (a) all waves done reading buf[cur^1] last
    // iter (kt=0: done reading Q frags from region 0), (b) this wave's
    // outstanding STAGE loads into buf[cur] drained (vmcnt(0) before barrier).
    __syncthreads();
    if (kt < SEQ / 64 - 1) STAGE(cur ^ 1, kt + 1);  // fly under the compute

    char* Ks = smem + cur * 16384;
    char* Vs = Ks + 8192;

    // S = Q K^T (Q pre-scaled)
    f32x4 sacc[2][4];
#pragma unroll
    for (int mi = 0; mi < 2; mi++)
#pragma unroll
      for (int ni = 0; ni < 4; ni++) sacc[mi][ni] = fzero;
#pragma unroll
    for (int ks = 0; ks < 2; ks++) {
      bf16x8 kf[4];
      int byt = ks * 64 + lhi * 16;
#pragma unroll
      for (int ni = 0; ni < 4; ni++) {
        int r = ni * 16 + l15;
        kf[ni] = *(const bf16x8*)(Ks + r * 128 + (byt ^ ((r & 7) << 4)));
      }
#pragma unroll
      for (int mi = 0; mi < 2; mi++)
#pragma unroll
        for (int ni = 0; ni < 4; ni++)
          sacc[mi][ni] = __builtin_amdgcn_mfma_f32_16x16x32_bf16(
              qf[mi][ks], kf[ni], sacc[mi][ni], 0, 0, 0);
    }

    // online softmax: row = w*32 + mi*16 + lhi*4 + j, cols = ni*16 + l15
#pragma unroll
    for (int mi = 0; mi < 2; mi++)
#pragma unroll
      for (int j = 0; j < 4; j++) {
        float mx = fmaxf(fmaxf(sacc[mi][0][j], sacc[mi][1][j]),
                         fmaxf(sacc[mi][2][j], sacc[mi][3][j]));
        mx = fmaxf(mx, __shfl_xor(mx, 1, 64));
        mx = fmaxf(mx, __shfl_xor(mx, 2, 64));
        mx = fmaxf(mx, __shfl_xor(mx, 4, 64));
        mx = fmaxf(mx, __shfl_xor(mx, 8, 64));
        float mnew = fmaxf(mrun[mi][j], mx);
        float corr = __expf(mrun[mi][j] - mnew);  // first iter: exp(-inf)=0
        mrun[mi][j] = mnew;
        float p[4], ps = 0.f;
#pragma unroll
        for (int ni = 0; ni < 4; ni++) {
          p[ni] = __expf(sacc[mi][ni][j] - mnew);
          ps += p[ni];
        }
        ps += __shfl_xor(ps, 1, 64);
        ps += __shfl_xor(ps, 2, 64);
        ps += __shfl_xor(ps, 4, 64);
        ps += __shfl_xor(ps, 8, 64);
        lrun[mi][j] = lrun[mi][j] * corr + ps;
#pragma unroll
        for (int db = 0; db < 4; db++) oacc[mi][db][j] *= corr;
        // write P (bf16) into swizzled LDS for the PV A-operand
        int r = w * 32 + mi * 16 + lhi * 4 + j;
        int sw = (r & 7) << 4;
#pragma unroll
        for (int ni = 0; ni < 4; ni++) {
          int cb = (ni * 16 + l15) * 2;
          *(bf16_t*)(Ps + r * 128 + (cb ^ sw)) = (bf16_t)p[ni];
        }
      }

    // O += P V   (P rows are per-wave private: no barrier needed)
#pragma unroll
    for (int ks = 0; ks < 2; ks++) {
      bf16x8 pf[2], vf[4];
      int byt = ks * 64 + lhi * 16;
#pragma unroll
      for (int mi = 0; mi < 2; mi++) {
        int r = w * 32 + mi * 16 + l15;
        pf[mi] = *(const bf16x8*)(Ps + r * 128 + (byt ^ ((r & 7) << 4)));
      }
#pragma unroll
      for (int db = 0; db < 4; db++) {
        int r = db * 16 + l15;
        vf[db] = *(const bf16x8*)(Vs + r * 128 + (byt ^ ((r & 7) << 4)));
      }
#pragma unroll
      for (int mi = 0; mi < 2; mi++)
#pragma unroll
        for (int db = 0; db < 4; db++)
          oacc[mi][db] = __builtin_amdgcn_mfma_f32_16x16x32_bf16(
              pf[mi], vf[db], oacc[mi][db], 0, 0, 0);
    }
    cur ^= 1;
  }

  // epilogue: O[b, s, h*64+d] bf16
  const int b = bh >> 4, h = bh & 15;
#pragma unroll
  for (int mi = 0; mi < 2; mi++)
#pragma unroll
    for (int db = 0; db < 4; db++)
#pragma unroll
      for (int j = 0; j < 4; j++) {
        int srow = qt * 128 + w * 32 + mi * 16 + lhi * 4 + j;
        int d = db * 16 + l15;
        float v = oacc[mi][db][j] / lrun[mi][j];
        Og[((size_t)b * SEQ + srow) * DMODEL + h * HDIM + d] = (bf16_t)v;
      }
}

// ------------------------------------------------------------------- launch
extern "C" void kernel_launch(void* const* d_in, const int* in_sizes, int n_in,
                              void* d_out, int out_size, void* d_ws,
                              size_t ws_size, hipStream_t stream) {
  (void)in_sizes; (void)n_in; (void)out_size; (void)ws_size;
  const float* x     = (const float*)d_in[0];
  const float* w_in  = (const float*)d_in[1];
  const float* b_in  = (const float*)d_in[2];
  const float* w_out = (const float*)d_in[3];
  const float* b_out = (const float*)d_in[4];
  float* out = (float*)d_out;

  char* ws = (char*)d_ws;
  bf16_t* xb  = (bf16_t*)ws; ws += (size_t)MROWS * KDIM * 2;    // 16 MB
  bf16_t* wqb = (bf16_t*)ws; ws += (size_t)NQKV * KDIM * 2;     //  6 MB
  bf16_t* wob = (bf16_t*)ws; ws += (size_t)DMODEL * KDIM * 2;   //  2 MB
  bf16_t* Qg  = (bf16_t*)ws; ws += (size_t)MROWS * DMODEL * 2;  // 16 MB
  bf16_t* Kg  = (bf16_t*)ws; ws += (size_t)MROWS * DMODEL * 2;  // 16 MB
  bf16_t* Vt  = (bf16_t*)ws; ws += (size_t)MROWS * DMODEL * 2;  // 16 MB
  bf16_t* Og  = (bf16_t*)ws; ws += (size_t)MROWS * DMODEL * 2;  // 16 MB

  cast_f32_to_bf16<<<2048, 256, 0, stream>>>(x, xb, MROWS * KDIM / 4);
  cast_f32_to_bf16<<<1024, 256, 0, stream>>>(w_in, wqb, NQKV * KDIM / 4);
  cast_f32_to_bf16<<<512, 256, 0, stream>>>(w_out, wob, DMODEL * KDIM / 4);

  gemm_qkv_kernel<<<64 * 24, 256, 0, stream>>>(xb, wqb, b_in, Qg, Kg, Vt);
  attn_kernel<<<64 * 16, 256, 0, stream>>>(Qg, Kg, Vt, Og);
  gemm_out_kernel<<<64 * 8, 256, 0, stream>>>(Og, wob, b_out, out);
}

// Round 6
// 383.481 us; speedup vs baseline: 1.9377x; 1.7140x over previous
//
#include <hip/hip_runtime.h>
#include <hip/hip_bf16.h>
#include <math.h>

typedef __bf16 bf16_t;
typedef __bf16 bf16x8 __attribute__((ext_vector_type(8)));
typedef float  f32x4  __attribute__((ext_vector_type(4)));

#define DEV __device__ __forceinline__

#define BSZ    4
#define SEQ    2048
#define DMODEL 1024
#define NHEADS 16
#define HDIM   64
#define MROWS  (BSZ*SEQ)      /* 8192 */
#define KDIM   1024           /* K for both GEMMs */
#define NQKV   (3*DMODEL)     /* 3072 */

// async global->LDS, 16B per lane; LDS dest must be wave-uniform base + lane*16
#define GLOAD_LDS16(src, dst)                                                  \
  __builtin_amdgcn_global_load_lds(                                            \
      (__attribute__((address_space(1))) void*)(void*)(src),                   \
      (__attribute__((address_space(3))) void*)(dst), 16, 0, 0)

// ---------------------------------------------------------------- cast kernel
__global__ void cast_f32_to_bf16(const float* __restrict__ in,
                                 bf16_t* __restrict__ out, int n4) {
  union U { bf16_t b[4]; uint2 u; };
  for (int i = blockIdx.x * blockDim.x + threadIdx.x; i < n4;
       i += gridDim.x * blockDim.x) {
    float4 v = reinterpret_cast<const float4*>(in)[i];
    U r;
    r.b[0] = (bf16_t)v.x; r.b[1] = (bf16_t)v.y;
    r.b[2] = (bf16_t)v.z; r.b[3] = (bf16_t)v.w;
    reinterpret_cast<uint2*>(out)[i] = r.u;
  }
}

// ---------------------------------------------------------------- GEMM core
// C_tile[128x128] = A[row0:+128, 0:1024] * Bt[col0:+128, 0:1024]^T
// A, Bt row-major bf16 with K contiguous. LDS tiles are [128 rows][128 bytes]
// with byte ^= ((row&7)<<4) XOR swizzle; staging pre-swizzles the GLOBAL source
// so the linear global_load_lds dest stays correct (guide §5 / m173 pattern).
DEV void gemm_tile(const bf16_t* __restrict__ A, const bf16_t* __restrict__ Bt,
                   int row0, int col0, char* smem, f32x4 acc[4][4]) {
  const int t    = threadIdx.x;
  const int lane = t & 63;
  const int wid  = t >> 6;
  const int wm   = (wid >> 1) * 64;
  const int wn   = (wid & 1) * 64;
  const int l15  = lane & 15;
  const int lhi  = lane >> 4;

  char* As = smem;
  char* Bs = smem + 16384;

  const f32x4 fzero = {0.f, 0.f, 0.f, 0.f};
#pragma unroll
  for (int mi = 0; mi < 4; mi++)
#pragma unroll
    for (int ni = 0; ni < 4; ni++) acc[mi][ni] = fzero;

  const char* Abase = (const char*)A;
  const char* Bbase = (const char*)Bt;

  for (int k0 = 0; k0 < KDIM; k0 += 64) {
    __syncthreads();  // previous iter's LDS reads complete
#pragma unroll
    for (int i = 0; i < 4; i++) {
      int o   = (t + i * 256) * 16;                 // 0..16K-16
      int row = o >> 7;
      int cbs = (o & 127) ^ ((row & 7) << 4);       // pre-swizzled source col
      GLOAD_LDS16(Abase + ((size_t)(row0 + row) * KDIM + k0) * 2 + cbs, As + o);
      GLOAD_LDS16(Bbase + ((size_t)(col0 + row) * KDIM + k0) * 2 + cbs, Bs + o);
    }
    __syncthreads();  // drains vmcnt: tiles ready

#pragma unroll
    for (int ks = 0; ks < 2; ks++) {
      bf16x8 a[4], b[4];
      int byt = ks * 64 + lhi * 16;
#pragma unroll
      for (int mi = 0; mi < 4; mi++) {
        int r = wm + mi * 16 + l15;
        a[mi] = *(const bf16x8*)(As + r * 128 + (byt ^ ((r & 7) << 4)));
      }
#pragma unroll
      for (int ni = 0; ni < 4; ni++) {
        int r = wn + ni * 16 + l15;
        b[ni] = *(const bf16x8*)(Bs + r * 128 + (byt ^ ((r & 7) << 4)));
      }
#pragma unroll
      for (int mi = 0; mi < 4; mi++)
#pragma unroll
        for (int ni = 0; ni < 4; ni++)
          acc[mi][ni] = __builtin_amdgcn_mfma_f32_16x16x32_bf16(
              a[mi], b[ni], acc[mi][ni], 0, 0, 0);
    }
  }
}

// ------------------------------------------------- QKV projection + scatter
// qkv[m, n] = x[m,:] . W[n,:] + bias[n];  n<1024 -> Q, <2048 -> K, else -> V
// Q,K stored [b*16+h][s][64]; V stored TRANSPOSED [b*16+h][d][2048].
// Q is pre-scaled by hd^-0.5 so attention softmax works on raw QK^T.
__global__ void gemm_qkv_kernel(const bf16_t* __restrict__ xb,
                                const bf16_t* __restrict__ wqkv,
                                const float* __restrict__ bias,
                                bf16_t* __restrict__ Qg, bf16_t* __restrict__ Kg,
                                bf16_t* __restrict__ Vt) {
  __shared__ char smem[32768];
  f32x4 acc[4][4];
  const int bx = blockIdx.x;
  const int mt = bx / 24, nt = bx % 24;
  const int row0 = mt * 128, col0 = nt * 128;
  gemm_tile(xb, wqkv, row0, col0, smem, acc);

  const int t = threadIdx.x, lane = t & 63, wid = t >> 6;
  const int wm = (wid >> 1) * 64, wn = (wid & 1) * 64;
  const int l15 = lane & 15, lhi = lane >> 4;
#pragma unroll
  for (int mi = 0; mi < 4; mi++)
#pragma unroll
    for (int ni = 0; ni < 4; ni++)
#pragma unroll
      for (int j = 0; j < 4; j++) {
        int m = row0 + wm + mi * 16 + lhi * 4 + j;
        int n = col0 + wn + ni * 16 + l15;
        float v = acc[mi][ni][j] + bias[n];
        int b = m >> 11, s = m & 2047;
        int which = n >> 10, rem = n & 1023;
        int h = rem >> 6, d = rem & 63;
        size_t bh = (size_t)(b * NHEADS + h);
        if (which == 0) {
          Qg[(bh * SEQ + s) * HDIM + d] = (bf16_t)(v * 0.125f);
        } else if (which == 1) {
          Kg[(bh * SEQ + s) * HDIM + d] = (bf16_t)v;
        } else {
          Vt[(bh * HDIM + d) * SEQ + s] = (bf16_t)v;
        }
      }
}

// ------------------------------------------------------------ out projection
__global__ void gemm_out_kernel(const bf16_t* __restrict__ Og,
                                const bf16_t* __restrict__ wo,
                                const float* __restrict__ bias,
                                float* __restrict__ out) {
  __shared__ char smem[32768];
  f32x4 acc[4][4];
  const int bx = blockIdx.x;
  const int mt = bx >> 3, nt = bx & 7;
  const int row0 = mt * 128, col0 = nt * 128;
  gemm_tile(Og, wo, row0, col0, smem, acc);

  const int t = threadIdx.x, lane = t & 63, wid = t >> 6;
  const int wm = (wid >> 1) * 64, wn = (wid & 1) * 64;
  const int l15 = lane & 15, lhi = lane >> 4;
#pragma unroll
  for (int mi = 0; mi < 4; mi++)
#pragma unroll
    for (int ni = 0; ni < 4; ni++)
#pragma unroll
      for (int j = 0; j < 4; j++) {
        int m = row0 + wm + mi * 16 + lhi * 4 + j;
        int n = col0 + wn + ni * 16 + l15;
        out[(size_t)m * DMODEL + n] = acc[mi][ni][j] + bias[n];
      }
}

// ------------------------------------------------------------ flash attention
// R2-proven math (passed, absmax 2e-3). grid = 1024, XCD-aware remap,
// 4 waves x 32 q-rows, KVBLK=64, K/V double-buffered 2-phase pipeline.
// ONLY change vs R2: __launch_bounds__(256,4) -> VGPR budget 128 (was 64),
// unlocking ILP across the 8 independent softmax row-chains that R2's
// register starvation serialized (theory: VALUBusy 16% / all-idle profile).
__global__ __launch_bounds__(256, 4)
void attn_kernel(const bf16_t* __restrict__ Qg,
                 const bf16_t* __restrict__ Kg,
                 const bf16_t* __restrict__ Vt,
                 bf16_t* __restrict__ Og) {
  __shared__ char smem[49152];
  // buf0: [0,16384)  = K(8KB)+V(8KB)   (also initial Q staging area)
  // buf1: [16384,32768) = K+V
  // Ps:   [32768,49152)
  char* Ps = smem + 32768;

  const int t = threadIdx.x, lane = t & 63, w = t >> 6;
  const int l15 = lane & 15, lhi = lane >> 4;

  const int xcd = blockIdx.x & 7, slot = blockIdx.x >> 3;
  const int bh = xcd * 8 + (slot >> 4), qt = slot & 15;

  const char* Qb = (const char*)Qg + ((size_t)bh * SEQ + qt * 128) * HDIM * 2;
  const char* Kb = (const char*)Kg + (size_t)bh * SEQ * HDIM * 2;
  const char* Vb = (const char*)Vt + (size_t)bh * HDIM * SEQ * 2;

  // stage K/V tile for a kv-step into buffer `buf`
  auto STAGE = [&](int buf, int kt) {
    char* Kd = smem + buf * 16384;
    char* Vd = Kd + 8192;
#pragma unroll
    for (int i = 0; i < 2; i++) {
      int o   = (t + i * 256) * 16;            // 0..8176
      int row = o >> 7;                        // 0..63
      int cbs = (o & 127) ^ ((row & 7) << 4);  // pre-swizzled source col
      GLOAD_LDS16(Kb + (size_t)(kt * 64 + row) * 128 + cbs, Kd + o);
      GLOAD_LDS16(Vb + (size_t)row * 4096 + kt * 128 + cbs, Vd + o);
    }
  };

  // prologue: Q tile -> buf0 region, K/V tile 0 -> buf1, concurrently
#pragma unroll
  for (int i = 0; i < 4; i++) {
    int o = (t + i * 256) * 16;
    int row = o >> 7;
    int cbs = (o & 127) ^ ((row & 7) << 4);
    GLOAD_LDS16(Qb + (size_t)row * 128 + cbs, smem + o);
  }
  STAGE(1, 0);
  __syncthreads();  // Q + tile0 staged (vmcnt drained)

  // Q fragments -> registers for the whole kernel (Q already scaled by 1/8)
  bf16x8 qf[2][2];
#pragma unroll
  for (int mi = 0; mi < 2; mi++)
#pragma unroll
    for (int ks = 0; ks < 2; ks++) {
      int r = w * 32 + mi * 16 + l15;
      int byt = ks * 64 + lhi * 16;
      qf[mi][ks] = *(const bf16x8*)(smem + r * 128 + (byt ^ ((r & 7) << 4)));
    }

  const f32x4 fzero = {0.f, 0.f, 0.f, 0.f};
  float mrun[2][4], lrun[2][4];
  f32x4 oacc[2][4];
#pragma unroll
  for (int mi = 0; mi < 2; mi++) {
#pragma unroll
    for (int j = 0; j < 4; j++) { mrun[mi][j] = -INFINITY; lrun[mi][j] = 0.f; }
#pragma unroll
    for (int db = 0; db < 4; db++) oacc[mi][db] = fzero;
  }

  int cur = 1;
  for (int kt = 0; kt < SEQ / 64; kt++) {
    // single barrier per iter: (a) all waves done reading buf[cur^1] last
    // iter (kt=0: done reading Q frags from region 0), (b) this wave's
    // outstanding STAGE loads into buf[cur] drained (vmcnt(0) before barrier).
    __syncthreads();
    if (kt < SEQ / 64 - 1) STAGE(cur ^ 1, kt + 1);  // fly under the compute

    char* Ks = smem + cur * 16384;
    char* Vs = Ks + 8192;

    // S = Q K^T (Q pre-scaled)
    f32x4 sacc[2][4];
#pragma unroll
    for (int mi = 0; mi < 2; mi++)
#pragma unroll
      for (int ni = 0; ni < 4; ni++) sacc[mi][ni] = fzero;
#pragma unroll
    for (int ks = 0; ks < 2; ks++) {
      bf16x8 kf[4];
      int byt = ks * 64 + lhi * 16;
#pragma unroll
      for (int ni = 0; ni < 4; ni++) {
        int r = ni * 16 + l15;
        kf[ni] = *(const bf16x8*)(Ks + r * 128 + (byt ^ ((r & 7) << 4)));
      }
#pragma unroll
      for (int mi = 0; mi < 2; mi++)
#pragma unroll
        for (int ni = 0; ni < 4; ni++)
          sacc[mi][ni] = __builtin_amdgcn_mfma_f32_16x16x32_bf16(
              qf[mi][ks], kf[ni], sacc[mi][ni], 0, 0, 0);
    }

    // online softmax: row = w*32 + mi*16 + lhi*4 + j, cols = ni*16 + l15
#pragma unroll
    for (int mi = 0; mi < 2; mi++)
#pragma unroll
      for (int j = 0; j < 4; j++) {
        float mx = fmaxf(fmaxf(sacc[mi][0][j], sacc[mi][1][j]),
                         fmaxf(sacc[mi][2][j], sacc[mi][3][j]));
        mx = fmaxf(mx, __shfl_xor(mx, 1, 64));
        mx = fmaxf(mx, __shfl_xor(mx, 2, 64));
        mx = fmaxf(mx, __shfl_xor(mx, 4, 64));
        mx = fmaxf(mx, __shfl_xor(mx, 8, 64));
        float mnew = fmaxf(mrun[mi][j], mx);
        float corr = __expf(mrun[mi][j] - mnew);  // first iter: exp(-inf)=0
        mrun[mi][j] = mnew;
        float p[4], ps = 0.f;
#pragma unroll
        for (int ni = 0; ni < 4; ni++) {
          p[ni] = __expf(sacc[mi][ni][j] - mnew);
          ps += p[ni];
        }
        ps += __shfl_xor(ps, 1, 64);
        ps += __shfl_xor(ps, 2, 64);
        ps += __shfl_xor(ps, 4, 64);
        ps += __shfl_xor(ps, 8, 64);
        lrun[mi][j] = lrun[mi][j] * corr + ps;
#pragma unroll
        for (int db = 0; db < 4; db++) oacc[mi][db][j] *= corr;
        // write P (bf16) into swizzled LDS for the PV A-operand
        int r = w * 32 + mi * 16 + lhi * 4 + j;
        int sw = (r & 7) << 4;
#pragma unroll
        for (int ni = 0; ni < 4; ni++) {
          int cb = (ni * 16 + l15) * 2;
          *(bf16_t*)(Ps + r * 128 + (cb ^ sw)) = (bf16_t)p[ni];
        }
      }

    // O += P V   (P rows are per-wave private: no barrier needed)
#pragma unroll
    for (int ks = 0; ks < 2; ks++) {
      bf16x8 pf[2], vf[4];
      int byt = ks * 64 + lhi * 16;
#pragma unroll
      for (int mi = 0; mi < 2; mi++) {
        int r = w * 32 + mi * 16 + l15;
        pf[mi] = *(const bf16x8*)(Ps + r * 128 + (byt ^ ((r & 7) << 4)));
      }
#pragma unroll
      for (int db = 0; db < 4; db++) {
        int r = db * 16 + l15;
        vf[db] = *(const bf16x8*)(Vs + r * 128 + (byt ^ ((r & 7) << 4)));
      }
#pragma unroll
      for (int mi = 0; mi < 2; mi++)
#pragma unroll
        for (int db = 0; db < 4; db++)
          oacc[mi][db] = __builtin_amdgcn_mfma_f32_16x16x32_bf16(
              pf[mi], vf[db], oacc[mi][db], 0, 0, 0);
    }
    cur ^= 1;
  }

  // epilogue: O[b, s, h*64+d] bf16
  const int b = bh >> 4, h = bh & 15;
#pragma unroll
  for (int mi = 0; mi < 2; mi++)
#pragma unroll
    for (int db = 0; db < 4; db++)
#pragma unroll
      for (int j = 0; j < 4; j++) {
        int srow = qt * 128 + w * 32 + mi * 16 + lhi * 4 + j;
        int d = db * 16 + l15;
        float v = oacc[mi][db][j] / lrun[mi][j];
        Og[((size_t)b * SEQ + srow) * DMODEL + h * HDIM + d] = (bf16_t)v;
      }
}

// ------------------------------------------------------------------- launch
extern "C" void kernel_launch(void* const* d_in, const int* in_sizes, int n_in,
                              void* d_out, int out_size, void* d_ws,
                              size_t ws_size, hipStream_t stream) {
  (void)in_sizes; (void)n_in; (void)out_size; (void)ws_size;
  const float* x     = (const float*)d_in[0];
  const float* w_in  = (const float*)d_in[1];
  const float* b_in  = (const float*)d_in[2];
  const float* w_out = (const float*)d_in[3];
  const float* b_out = (const float*)d_in[4];
  float* out = (float*)d_out;

  char* ws = (char*)d_ws;
  bf16_t* xb  = (bf16_t*)ws; ws += (size_t)MROWS * KDIM * 2;    // 16 MB
  bf16_t* wqb = (bf16_t*)ws; ws += (size_t)NQKV * KDIM * 2;     //  6 MB
  bf16_t* wob = (bf16_t*)ws; ws += (size_t)DMODEL * KDIM * 2;   //  2 MB
  bf16_t* Qg  = (bf16_t*)ws; ws += (size_t)MROWS * DMODEL * 2;  // 16 MB
  bf16_t* Kg  = (bf16_t*)ws; ws += (size_t)MROWS * DMODEL * 2;  // 16 MB
  bf16_t* Vt  = (bf16_t*)ws; ws += (size_t)MROWS * DMODEL * 2;  // 16 MB
  bf16_t* Og  = (bf16_t*)ws; ws += (size_t)MROWS * DMODEL * 2;  // 16 MB

  cast_f32_to_bf16<<<2048, 256, 0, stream>>>(x, xb, MROWS * KDIM / 4);
  cast_f32_to_bf16<<<1024, 256, 0, stream>>>(w_in, wqb, NQKV * KDIM / 4);
  cast_f32_to_bf16<<<512, 256, 0, stream>>>(w_out, wob, DMODEL * KDIM / 4);

  gemm_qkv_kernel<<<64 * 24, 256, 0, stream>>>(xb, wqb, b_in, Qg, Kg, Vt);
  attn_kernel<<<64 * 16, 256, 0, stream>>>(Qg, Kg, Vt, Og);
  gemm_out_kernel<<<64 * 8, 256, 0, stream>>>(Og, wob, b_out, out);
}

// Round 7
// 237.652 us; speedup vs baseline: 3.1267x; 1.6136x over previous
//
#include <hip/hip_runtime.h>
#include <hip/hip_bf16.h>
#include <math.h>

typedef __bf16 bf16_t;
typedef __bf16 bf16x8 __attribute__((ext_vector_type(8)));
typedef float  f32x4  __attribute__((ext_vector_type(4)));

#define DEV __device__ __forceinline__

#define BSZ    4
#define SEQ    2048
#define DMODEL 1024
#define NHEADS 16
#define HDIM   64
#define MROWS  (BSZ*SEQ)      /* 8192 */
#define KDIM   1024           /* K for both GEMMs */
#define NQKV   (3*DMODEL)     /* 3072 */

// async global->LDS, 16B per lane; LDS dest must be wave-uniform base + lane*16
#define GLOAD_LDS16(src, dst)                                                  \
  __builtin_amdgcn_global_load_lds(                                            \
      (__attribute__((address_space(1))) void*)(void*)(src),                   \
      (__attribute__((address_space(3))) void*)(dst), 16, 0, 0)

// ---------------------------------------------------------------- cast kernel
__global__ void cast_f32_to_bf16(const float* __restrict__ in,
                                 bf16_t* __restrict__ out, int n4) {
  union U { bf16_t b[4]; uint2 u; };
  for (int i = blockIdx.x * blockDim.x + threadIdx.x; i < n4;
       i += gridDim.x * blockDim.x) {
    float4 v = reinterpret_cast<const float4*>(in)[i];
    U r;
    r.b[0] = (bf16_t)v.x; r.b[1] = (bf16_t)v.y;
    r.b[2] = (bf16_t)v.z; r.b[3] = (bf16_t)v.w;
    reinterpret_cast<uint2*>(out)[i] = r.u;
  }
}

// ---------------------------------------------------------------- GEMM core
// C_tile[128x128] = A[row0:+128, 0:1024] * Bt[col0:+128, 0:1024]^T
// A, Bt row-major bf16 with K contiguous. LDS tiles are [128 rows][128 bytes]
// with byte ^= ((row&7)<<4) XOR swizzle; staging pre-swizzles the GLOBAL source
// so the linear global_load_lds dest stays correct (guide §5 / m173 pattern).
DEV void gemm_tile(const bf16_t* __restrict__ A, const bf16_t* __restrict__ Bt,
                   int row0, int col0, char* smem, f32x4 acc[4][4]) {
  const int t    = threadIdx.x;
  const int lane = t & 63;
  const int wid  = t >> 6;
  const int wm   = (wid >> 1) * 64;
  const int wn   = (wid & 1) * 64;
  const int l15  = lane & 15;
  const int lhi  = lane >> 4;

  char* As = smem;
  char* Bs = smem + 16384;

  const f32x4 fzero = {0.f, 0.f, 0.f, 0.f};
#pragma unroll
  for (int mi = 0; mi < 4; mi++)
#pragma unroll
    for (int ni = 0; ni < 4; ni++) acc[mi][ni] = fzero;

  const char* Abase = (const char*)A;
  const char* Bbase = (const char*)Bt;

  for (int k0 = 0; k0 < KDIM; k0 += 64) {
    __syncthreads();  // previous iter's LDS reads complete
#pragma unroll
    for (int i = 0; i < 4; i++) {
      int o   = (t + i * 256) * 16;                 // 0..16K-16
      int row = o >> 7;
      int cbs = (o & 127) ^ ((row & 7) << 4);       // pre-swizzled source col
      GLOAD_LDS16(Abase + ((size_t)(row0 + row) * KDIM + k0) * 2 + cbs, As + o);
      GLOAD_LDS16(Bbase + ((size_t)(col0 + row) * KDIM + k0) * 2 + cbs, Bs + o);
    }
    __syncthreads();  // drains vmcnt: tiles ready

#pragma unroll
    for (int ks = 0; ks < 2; ks++) {
      bf16x8 a[4], b[4];
      int byt = ks * 64 + lhi * 16;
#pragma unroll
      for (int mi = 0; mi < 4; mi++) {
        int r = wm + mi * 16 + l15;
        a[mi] = *(const bf16x8*)(As + r * 128 + (byt ^ ((r & 7) << 4)));
      }
#pragma unroll
      for (int ni = 0; ni < 4; ni++) {
        int r = wn + ni * 16 + l15;
        b[ni] = *(const bf16x8*)(Bs + r * 128 + (byt ^ ((r & 7) << 4)));
      }
#pragma unroll
      for (int mi = 0; mi < 4; mi++)
#pragma unroll
        for (int ni = 0; ni < 4; ni++)
          acc[mi][ni] = __builtin_amdgcn_mfma_f32_16x16x32_bf16(
              a[mi], b[ni], acc[mi][ni], 0, 0, 0);
    }
  }
}

// ------------------------------------------------- QKV projection + scatter
// qkv[m, n] = x[m,:] . W[n,:] + bias[n];  n<1024 -> Q, <2048 -> K, else -> V
// Q,K stored [b*16+h][s][64]; V stored TRANSPOSED [b*16+h][d][2048].
// Q is pre-scaled by hd^-0.5 so attention softmax works on raw QK^T.
__global__ void gemm_qkv_kernel(const bf16_t* __restrict__ xb,
                                const bf16_t* __restrict__ wqkv,
                                const float* __restrict__ bias,
                                bf16_t* __restrict__ Qg, bf16_t* __restrict__ Kg,
                                bf16_t* __restrict__ Vt) {
  __shared__ char smem[32768];
  f32x4 acc[4][4];
  const int bx = blockIdx.x;
  const int mt = bx / 24, nt = bx % 24;
  const int row0 = mt * 128, col0 = nt * 128;
  gemm_tile(xb, wqkv, row0, col0, smem, acc);

  const int t = threadIdx.x, lane = t & 63, wid = t >> 6;
  const int wm = (wid >> 1) * 64, wn = (wid & 1) * 64;
  const int l15 = lane & 15, lhi = lane >> 4;
#pragma unroll
  for (int mi = 0; mi < 4; mi++)
#pragma unroll
    for (int ni = 0; ni < 4; ni++)
#pragma unroll
      for (int j = 0; j < 4; j++) {
        int m = row0 + wm + mi * 16 + lhi * 4 + j;
        int n = col0 + wn + ni * 16 + l15;
        float v = acc[mi][ni][j] + bias[n];
        int b = m >> 11, s = m & 2047;
        int which = n >> 10, rem = n & 1023;
        int h = rem >> 6, d = rem & 63;
        size_t bh = (size_t)(b * NHEADS + h);
        if (which == 0) {
          Qg[(bh * SEQ + s) * HDIM + d] = (bf16_t)(v * 0.125f);
        } else if (which == 1) {
          Kg[(bh * SEQ + s) * HDIM + d] = (bf16_t)v;
        } else {
          Vt[(bh * HDIM + d) * SEQ + s] = (bf16_t)v;
        }
      }
}

// ------------------------------------------------------------ out projection
__global__ void gemm_out_kernel(const bf16_t* __restrict__ Og,
                                const bf16_t* __restrict__ wo,
                                const float* __restrict__ bias,
                                float* __restrict__ out) {
  __shared__ char smem[32768];
  f32x4 acc[4][4];
  const int bx = blockIdx.x;
  const int mt = bx >> 3, nt = bx & 7;
  const int row0 = mt * 128, col0 = nt * 128;
  gemm_tile(Og, wo, row0, col0, smem, acc);

  const int t = threadIdx.x, lane = t & 63, wid = t >> 6;
  const int wm = (wid >> 1) * 64, wn = (wid & 1) * 64;
  const int l15 = lane & 15, lhi = lane >> 4;
#pragma unroll
  for (int mi = 0; mi < 4; mi++)
#pragma unroll
    for (int ni = 0; ni < 4; ni++)
#pragma unroll
      for (int j = 0; j < 4; j++) {
        int m = row0 + wm + mi * 16 + lhi * 4 + j;
        int n = col0 + wn + ni * 16 + l15;
        out[(size_t)m * DMODEL + n] = acc[mi][ni][j] + bias[n];
      }
}

// ------------------------------------------------------------ flash attention
// R6-proven structure (302 us). Changes this round (both bounded-math):
//  1. T13 defer-max: skip max-reduce/rescale/m-update unless any lane's local
//     4-col max exceeds mrun+8 (wave-uniform __any). P bounded by e^8; scale
//     cancels in O = sum(P V)/sum(P). First iter (mrun=-inf) always full-path.
//  2. Deferred sum-reduce: corr is row-uniform, so accumulate per-LANE partial
//     sums (lpart) and cross-lane-reduce ONCE in the epilogue.
// Common-case per-iter cross-lane ops: 64 shfls -> 0.
__global__ __launch_bounds__(256, 4)
void attn_kernel(const bf16_t* __restrict__ Qg,
                 const bf16_t* __restrict__ Kg,
                 const bf16_t* __restrict__ Vt,
                 bf16_t* __restrict__ Og) {
  __shared__ char smem[49152];
  // buf0: [0,16384)  = K(8KB)+V(8KB)   (also initial Q staging area)
  // buf1: [16384,32768) = K+V
  // Ps:   [32768,49152)
  char* Ps = smem + 32768;

  const int t = threadIdx.x, lane = t & 63, w = t >> 6;
  const int l15 = lane & 15, lhi = lane >> 4;

  const int xcd = blockIdx.x & 7, slot = blockIdx.x >> 3;
  const int bh = xcd * 8 + (slot >> 4), qt = slot & 15;

  const char* Qb = (const char*)Qg + ((size_t)bh * SEQ + qt * 128) * HDIM * 2;
  const char* Kb = (const char*)Kg + (size_t)bh * SEQ * HDIM * 2;
  const char* Vb = (const char*)Vt + (size_t)bh * HDIM * SEQ * 2;

  // stage K/V tile for a kv-step into buffer `buf`
  auto STAGE = [&](int buf, int kt) {
    char* Kd = smem + buf * 16384;
    char* Vd = Kd + 8192;
#pragma unroll
    for (int i = 0; i < 2; i++) {
      int o   = (t + i * 256) * 16;            // 0..8176
      int row = o >> 7;                        // 0..63
      int cbs = (o & 127) ^ ((row & 7) << 4);  // pre-swizzled source col
      GLOAD_LDS16(Kb + (size_t)(kt * 64 + row) * 128 + cbs, Kd + o);
      GLOAD_LDS16(Vb + (size_t)row * 4096 + kt * 128 + cbs, Vd + o);
    }
  };

  // prologue: Q tile -> buf0 region, K/V tile 0 -> buf1, concurrently
#pragma unroll
  for (int i = 0; i < 4; i++) {
    int o = (t + i * 256) * 16;
    int row = o >> 7;
    int cbs = (o & 127) ^ ((row & 7) << 4);
    GLOAD_LDS16(Qb + (size_t)row * 128 + cbs, smem + o);
  }
  STAGE(1, 0);
  __syncthreads();  // Q + tile0 staged (vmcnt drained)

  // Q fragments -> registers for the whole kernel (Q already scaled by 1/8)
  bf16x8 qf[2][2];
#pragma unroll
  for (int mi = 0; mi < 2; mi++)
#pragma unroll
    for (int ks = 0; ks < 2; ks++) {
      int r = w * 32 + mi * 16 + l15;
      int byt = ks * 64 + lhi * 16;
      qf[mi][ks] = *(const bf16x8*)(smem + r * 128 + (byt ^ ((r & 7) << 4)));
    }

  const f32x4 fzero = {0.f, 0.f, 0.f, 0.f};
  float mrun[2][4], lpart[2][4];
  f32x4 oacc[2][4];
#pragma unroll
  for (int mi = 0; mi < 2; mi++) {
#pragma unroll
    for (int j = 0; j < 4; j++) { mrun[mi][j] = -INFINITY; lpart[mi][j] = 0.f; }
#pragma unroll
    for (int db = 0; db < 4; db++) oacc[mi][db] = fzero;
  }

  int cur = 1;
  for (int kt = 0; kt < SEQ / 64; kt++) {
    // single barrier per iter: (a) all waves done reading buf[cur^1] last
    // iter (kt=0: done reading Q frags from region 0), (b) this wave's
    // outstanding STAGE loads into buf[cur] drained (vmcnt(0) before barrier).
    __syncthreads();
    if (kt < SEQ / 64 - 1) STAGE(cur ^ 1, kt + 1);  // fly under the compute

    char* Ks = smem + cur * 16384;
    char* Vs = Ks + 8192;

    // S = Q K^T (Q pre-scaled)
    f32x4 sacc[2][4];
#pragma unroll
    for (int mi = 0; mi < 2; mi++)
#pragma unroll
      for (int ni = 0; ni < 4; ni++) sacc[mi][ni] = fzero;
#pragma unroll
    for (int ks = 0; ks < 2; ks++) {
      bf16x8 kf[4];
      int byt = ks * 64 + lhi * 16;
#pragma unroll
      for (int ni = 0; ni < 4; ni++) {
        int r = ni * 16 + l15;
        kf[ni] = *(const bf16x8*)(Ks + r * 128 + (byt ^ ((r & 7) << 4)));
      }
#pragma unroll
      for (int mi = 0; mi < 2; mi++)
#pragma unroll
        for (int ni = 0; ni < 4; ni++)
          sacc[mi][ni] = __builtin_amdgcn_mfma_f32_16x16x32_bf16(
              qf[mi][ks], kf[ni], sacc[mi][ni], 0, 0, 0);
    }

    // ---- deferred-max online softmax -----------------------------------
    float lm[2][4];
#pragma unroll
    for (int mi = 0; mi < 2; mi++)
#pragma unroll
      for (int j = 0; j < 4; j++)
        lm[mi][j] = fmaxf(fmaxf(sacc[mi][0][j], sacc[mi][1][j]),
                          fmaxf(sacc[mi][2][j], sacc[mi][3][j]));
    int need = 0;
#pragma unroll
    for (int mi = 0; mi < 2; mi++)
#pragma unroll
      for (int j = 0; j < 4; j++)
        need |= (lm[mi][j] > mrun[mi][j] + 8.0f) ? 1 : 0;

    if (__any(need)) {  // rare after the first tile (wave-uniform branch)
#pragma unroll
      for (int mi = 0; mi < 2; mi++)
#pragma unroll
        for (int j = 0; j < 4; j++) {
          float mx = lm[mi][j];
          mx = fmaxf(mx, __shfl_xor(mx, 1, 64));
          mx = fmaxf(mx, __shfl_xor(mx, 2, 64));
          mx = fmaxf(mx, __shfl_xor(mx, 4, 64));
          mx = fmaxf(mx, __shfl_xor(mx, 8, 64));
          float mnew = fmaxf(mrun[mi][j], mx);
          float corr = __expf(mrun[mi][j] - mnew);  // first iter: 0
          mrun[mi][j] = mnew;
          lpart[mi][j] *= corr;
#pragma unroll
          for (int db = 0; db < 4; db++) oacc[mi][db][j] *= corr;
        }
    }

#pragma unroll
    for (int mi = 0; mi < 2; mi++)
#pragma unroll
      for (int j = 0; j < 4; j++) {
        float p[4], ps = 0.f;
#pragma unroll
        for (int ni = 0; ni < 4; ni++) {
          p[ni] = __expf(sacc[mi][ni][j] - mrun[mi][j]);  // bounded by e^8
          ps += p[ni];
        }
        lpart[mi][j] += ps;  // per-lane partial; cross-lane reduce at the end
        // write P (bf16) into swizzled LDS for the PV A-operand
        int r = w * 32 + mi * 16 + lhi * 4 + j;
        int sw = (r & 7) << 4;
#pragma unroll
        for (int ni = 0; ni < 4; ni++) {
          int cb = (ni * 16 + l15) * 2;
          *(bf16_t*)(Ps + r * 128 + (cb ^ sw)) = (bf16_t)p[ni];
        }
      }

    // O += P V   (P rows are per-wave private: no barrier needed)
#pragma unroll
    for (int ks = 0; ks < 2; ks++) {
      bf16x8 pf[2], vf[4];
      int byt = ks * 64 + lhi * 16;
#pragma unroll
      for (int mi = 0; mi < 2; mi++) {
        int r = w * 32 + mi * 16 + l15;
        pf[mi] = *(const bf16x8*)(Ps + r * 128 + (byt ^ ((r & 7) << 4)));
      }
#pragma unroll
      for (int db = 0; db < 4; db++) {
        int r = db * 16 + l15;
        vf[db] = *(const bf16x8*)(Vs + r * 128 + (byt ^ ((r & 7) << 4)));
      }
#pragma unroll
      for (int mi = 0; mi < 2; mi++)
#pragma unroll
        for (int db = 0; db < 4; db++)
          oacc[mi][db] = __builtin_amdgcn_mfma_f32_16x16x32_bf16(
              pf[mi], vf[db], oacc[mi][db], 0, 0, 0);
    }
    cur ^= 1;
  }

  // epilogue: reduce lpart across the 16-lane row groups, then store O.
  float linv[2][4];
#pragma unroll
  for (int mi = 0; mi < 2; mi++)
#pragma unroll
    for (int j = 0; j < 4; j++) {
      float ls = lpart[mi][j];
      ls += __shfl_xor(ls, 1, 64);
      ls += __shfl_xor(ls, 2, 64);
      ls += __shfl_xor(ls, 4, 64);
      ls += __shfl_xor(ls, 8, 64);
      linv[mi][j] = 1.0f / ls;
    }
  const int b = bh >> 4, h = bh & 15;
#pragma unroll
  for (int mi = 0; mi < 2; mi++)
#pragma unroll
    for (int db = 0; db < 4; db++)
#pragma unroll
      for (int j = 0; j < 4; j++) {
        int srow = qt * 128 + w * 32 + mi * 16 + lhi * 4 + j;
        int d = db * 16 + l15;
        float v = oacc[mi][db][j] * linv[mi][j];
        Og[((size_t)b * SEQ + srow) * DMODEL + h * HDIM + d] = (bf16_t)v;
      }
}

// ------------------------------------------------------------------- launch
extern "C" void kernel_launch(void* const* d_in, const int* in_sizes, int n_in,
                              void* d_out, int out_size, void* d_ws,
                              size_t ws_size, hipStream_t stream) {
  (void)in_sizes; (void)n_in; (void)out_size; (void)ws_size;
  const float* x     = (const float*)d_in[0];
  const float* w_in  = (const float*)d_in[1];
  const float* b_in  = (const float*)d_in[2];
  const float* w_out = (const float*)d_in[3];
  const float* b_out = (const float*)d_in[4];
  float* out = (float*)d_out;

  char* ws = (char*)d_ws;
  bf16_t* xb  = (bf16_t*)ws; ws += (size_t)MROWS * KDIM * 2;    // 16 MB
  bf16_t* wqb = (bf16_t*)ws; ws += (size_t)NQKV * KDIM * 2;     //  6 MB
  bf16_t* wob = (bf16_t*)ws; ws += (size_t)DMODEL * KDIM * 2;   //  2 MB
  bf16_t* Qg  = (bf16_t*)ws; ws += (size_t)MROWS * DMODEL * 2;  // 16 MB
  bf16_t* Kg  = (bf16_t*)ws; ws += (size_t)MROWS * DMODEL * 2;  // 16 MB
  bf16_t* Vt  = (bf16_t*)ws; ws += (size_t)MROWS * DMODEL * 2;  // 16 MB
  bf16_t* Og  = (bf16_t*)ws; ws += (size_t)MROWS * DMODEL * 2;  // 16 MB

  cast_f32_to_bf16<<<2048, 256, 0, stream>>>(x, xb, MROWS * KDIM / 4);
  cast_f32_to_bf16<<<1024, 256, 0, stream>>>(w_in, wqb, NQKV * KDIM / 4);
  cast_f32_to_bf16<<<512, 256, 0, stream>>>(w_out, wob, DMODEL * KDIM / 4);

  gemm_qkv_kernel<<<64 * 24, 256, 0, stream>>>(xb, wqb, b_in, Qg, Kg, Vt);
  attn_kernel<<<64 * 16, 256, 0, stream>>>(Qg, Kg, Vt, Og);
  gemm_out_kernel<<<64 * 8, 256, 0, stream>>>(Og, wob, b_out, out);
}